// Round 16
// baseline (891.177 us; speedup 1.0000x reference)
//
#include <hip/hip_runtime.h>

// FHETinyGPT forward. R16: both pipelined GEMMs converted to the m201-style
// DOUBLE-BARRIER phase: {reads; stage; s_barrier; lgkmcnt(0); sched_barrier;
// setprio MFMA; sched_barrier; (vmcnt); s_barrier}. Reads fly during barrier-
// wait (wave skew + other waves' MFMA), so the MFMA cluster starts unblocked —
// removes the per-phase LDS-latency serialization that pinned the single-
// barrier K-loop at 38% MfmaUtil (R13/R15), while keeping R13's 2-blocks/CU
// fixed-cost overlap (R4's double-barrier at 1 block/CU had K-loop ~50-55%
// hidden under prologue/epilogue). Producer-side vmcnt unchanged (R13-proven).
//  - logits, fused q|k, vT, PV, o2: gemm_bt_256x128 (256x128, BK=32, 48KB LDS).
//  - QK^T: gemm_bt_256 (256^2, BK=64), strided q/k reads from fused qk buffer.
// Grid mappings (bijective, lin%8 = XCD):
//  SWZ=0 (M=8192): tm=(lin&7)*4+((lin>>3)&3), tn=lin>>5; SWZ=1 (M=2048):
//  tm=lin&7, tn=lin>>3; SWZ=2 (M=1024): tm=lin&3, tn=lin>>2.

typedef __bf16 bf16_t;
typedef __bf16 bf16x8 __attribute__((ext_vector_type(8)));
typedef __bf16 bf16x4 __attribute__((ext_vector_type(4)));
typedef float  f32x4  __attribute__((ext_vector_type(4)));

#define VOCAB 32000
#define DIM   1024
#define BATCH 4
#define SEQ   2048
#define BT    (BATCH*SEQ)   // 8192

__device__ __forceinline__ void gload_lds16(const void* g, void* l) {
    __builtin_amdgcn_global_load_lds(
        (const __attribute__((address_space(1))) void*)g,
        (__attribute__((address_space(3))) void*)l,
        16, 0, 0);
}

// ---------------- weight cast f32 -> bf16 ------------------------------------------
__global__ void cast_f32_to_bf16(const float* __restrict__ in, bf16_t* __restrict__ out, int n4) {
    int i = blockIdx.x * blockDim.x + threadIdx.x;
    if (i < n4) {
        float4 v = ((const float4*)in)[i];
        bf16x4 o;
        o.x = (bf16_t)v.x; o.y = (bf16_t)v.y; o.z = (bf16_t)v.z; o.w = (bf16_t)v.w;
        ((bf16x4*)out)[i] = o;
    }
}

// ---------------- h = emb_w[x] * 0.01 -> bf16 [BT, DIM] ----------------------------
__global__ void embed_gather(const int* __restrict__ x, const float* __restrict__ emb,
                             bf16_t* __restrict__ h) {
    const int tok = blockIdx.x;
    const int row = x[tok];
    const float4* src = (const float4*)(emb + (long)row * DIM);
    bf16x4* dst = (bf16x4*)(h + (long)tok * DIM);
    int j = threadIdx.x;
    float4 v = src[j];
    bf16x4 o;
    o.x = (bf16_t)(v.x * 0.01f); o.y = (bf16_t)(v.y * 0.01f);
    o.z = (bf16_t)(v.z * 0.01f); o.w = (bf16_t)(v.w * 0.01f);
    dst[j] = o;
}

#define BAR() asm volatile("s_barrier" ::: "memory")
#define LGKM0() do { asm volatile("s_waitcnt lgkmcnt(0)" ::: "memory");               \
                     __builtin_amdgcn_sched_barrier(0); } while (0)

// ---------------- 256x256 pipelined GEMM (double-barrier phases) -------------------
// C[M,N] = epi(scale * A[M,K] @ B[N,K]^T); A rows stride lda, B rows stride ldb.
// SWZ=1: grid (64,1,BATCH), M==N==2048 (QK^T).
template<int ACT, int SWZ, typename CT>
__global__ __launch_bounds__(512, 2) void gemm_bt_256(
    const bf16_t* __restrict__ A, const bf16_t* __restrict__ B, CT* __restrict__ C,
    int N, int K, int lda, int ldb, long sA, long sB, long sC, float scale)
{
    __shared__ __align__(16) char smem[131072];   // 2buf x (A 32KB + B 32KB)
    char* const sm = smem;

    const int bz = blockIdx.z;
    A += (long)bz * sA;  B += (long)bz * sB;  C += (long)bz * sC;

    const int lin = blockIdx.x;
    int tm, tn;
    if (SWZ == 0) { const int xcd = lin & 7, jj = lin >> 3; tm = xcd * 4 + (jj & 3); tn = jj >> 2; }
    else          { tm = lin & 7; tn = lin >> 3; }
    const long trow0 = (long)tm * 256, tcol0 = (long)tn * 256;

    const int tid  = threadIdx.x;
    const int lane = tid & 63;
    const int wave = tid >> 6;
    const int wm = wave >> 2;
    const int wn = wave & 3;
    const int lr = lane & 15;
    const int ko2 = (lane >> 4) * 16;
    const int rbase = lr * 64 + (ko2 ^ (((lr >> 1) & 3) << 4));

    const int o0 = tid * 16, o1 = 8192 + tid * 16;
    int sr0, sc0, sr1, sc1;
    {
        int ol = o0 ^ (((o0 >> 7) & 3) << 4);
        sr0 = ((ol >> 10) >> 1) * 16 + ((ol >> 6) & 15);
        sc0 = ((ol >> 10) & 1) * 32 + ((ol & 63) >> 1);
        ol = o1 ^ (((o1 >> 7) & 3) << 4);
        sr1 = ((ol >> 10) >> 1) * 16 + ((ol >> 6) & 15);
        sc1 = ((ol >> 10) & 1) * 32 + ((ol & 63) >> 1);
    }

    const bf16_t* Abase = A + trow0 * lda;
    const bf16_t* Bbase = B + tcol0 * ldb;

#define STAGE_HT(gbase, ld, kt, half, ldsh) do {                                      \
    gload_lds16((gbase) + (long)((half) * 128 + sr0) * (ld) + ((kt) * 64 + sc0), (ldsh) + o0); \
    gload_lds16((gbase) + (long)((half) * 128 + sr1) * (ld) + ((kt) * 64 + sc1), (ldsh) + o1); \
} while (0)

    f32x4 acc[8][4];
#pragma unroll
    for (int i = 0; i < 8; ++i)
#pragma unroll
        for (int j = 0; j < 4; ++j)
            acc[i][j] = (f32x4){0.f, 0.f, 0.f, 0.f};

    // Double-barrier phases: reads+stage issued pre-barrier (data valid since an
    // earlier barrier); reads complete during barrier wait; MFMA unblocked.
    // PHASE_LO ends with its own closing barrier; PHASE_HI leaves the closing
    // barrier to the caller (so P3 can insert the producer-side vmcnt first).
#define PHASE_LO(ks, ...) do {                                                        \
    bf16x8 af_[4];                                                                    \
    af_[0] = *(const bf16x8*)(ldsA + ((wm * 4 + 0) * 2 + (ks)) * 1024 + rbase);       \
    _Pragma("unroll")                                                                 \
    for (int c_ = 0; c_ < 4; ++c_)                                                    \
        bv_[c_] = *(const bf16x8*)(ldsB + (c_ >> 1) * 16384 +                         \
                      ((wn * 2 + (c_ & 1)) * 2 + (ks)) * 1024 + rbase);               \
    _Pragma("unroll")                                                                 \
    for (int i_ = 1; i_ < 4; ++i_)                                                    \
        af_[i_] = *(const bf16x8*)(ldsA +                                             \
                      ((wm * 4 + i_) * 2 + (ks)) * 1024 + rbase);                     \
    __VA_ARGS__;                                                                      \
    BAR();                                                                            \
    LGKM0();                                                                          \
    __builtin_amdgcn_s_setprio(1);                                                    \
    _Pragma("unroll")                                                                 \
    for (int i_ = 0; i_ < 4; ++i_)                                                    \
        _Pragma("unroll")                                                             \
        for (int c_ = 0; c_ < 4; ++c_)                                                \
            acc[i_][c_] = __builtin_amdgcn_mfma_f32_16x16x32_bf16(                    \
                af_[i_], bv_[c_], acc[i_][c_], 0, 0, 0);                              \
    __builtin_amdgcn_s_setprio(0);                                                    \
    __builtin_amdgcn_sched_barrier(0);                                                \
    BAR();                                                                            \
} while (0)

#define PHASE_HI(ks, ...) do {                                                        \
    bf16x8 af_[4];                                                                    \
    _Pragma("unroll")                                                                 \
    for (int i_ = 0; i_ < 4; ++i_)                                                    \
        af_[i_] = *(const bf16x8*)(ldsA + 16384 +                                     \
                      ((wm * 4 + i_) * 2 + (ks)) * 1024 + rbase);                     \
    __VA_ARGS__;                                                                      \
    BAR();                                                                            \
    LGKM0();                                                                          \
    __builtin_amdgcn_s_setprio(1);                                                    \
    _Pragma("unroll")                                                                 \
    for (int i_ = 0; i_ < 4; ++i_)                                                    \
        _Pragma("unroll")                                                             \
        for (int c_ = 0; c_ < 4; ++c_)                                                \
            acc[4 + i_][c_] = __builtin_amdgcn_mfma_f32_16x16x32_bf16(                \
                af_[i_], bv_[c_], acc[4 + i_][c_], 0, 0, 0);                          \
    __builtin_amdgcn_s_setprio(0);                                                    \
    __builtin_amdgcn_sched_barrier(0);                                                \
} while (0)

    {
        char* a0 = sm;
        char* b0 = sm + 32768;
        char* a1 = sm + 65536;
        char* b1 = sm + 65536 + 32768;
        STAGE_HT(Abase, lda, 0, 0, a0);
        STAGE_HT(Bbase, ldb, 0, 0, b0);
        STAGE_HT(Abase, lda, 0, 1, a0 + 16384);
        STAGE_HT(Bbase, ldb, 0, 1, b0 + 16384);
        STAGE_HT(Abase, lda, 1, 0, a1);
        STAGE_HT(Bbase, ldb, 1, 0, b1);
        asm volatile("s_waitcnt vmcnt(4)" ::: "memory");
        BAR();
    }

    const int NT = K / 64;
    for (int t = 0; t < NT; ++t) {
        const int buf = t & 1;
        char* ldsA  = sm + buf * 65536;
        char* ldsB  = ldsA + 32768;
        char* ldsAn = sm + (buf ^ 1) * 65536;
        char* ldsBn = ldsAn + 32768;
        bf16x8 bv_[4];

        PHASE_LO(0,
              if (t + 1 < NT) {
                  STAGE_HT(Abase, lda, t + 1, 1, ldsAn + 16384);
                  STAGE_HT(Bbase, ldb, t + 1, 1, ldsBn + 16384);
              });
        PHASE_HI(0, );
        BAR();
        PHASE_LO(1, );
        PHASE_HI(1,
              if (t + 2 < NT) {
                  STAGE_HT(Abase, lda, t + 2, 0, ldsA);
                  STAGE_HT(Bbase, ldb, t + 2, 0, ldsB);
              });
        if (t + 2 < NT) { asm volatile("s_waitcnt vmcnt(4)" ::: "memory"); }
        else            { asm volatile("s_waitcnt vmcnt(0)" ::: "memory"); }
        BAR();
    }

    const int erow = (lane >> 4) * 4;
    const int ecol = lane & 15;
#pragma unroll
    for (int a = 0; a < 8; ++a)
#pragma unroll
        for (int c = 0; c < 4; ++c)
#pragma unroll
            for (int r = 0; r < 4; ++r) {
                long row = trow0 + (a >> 2) * 128 + wm * 64 + (a & 3) * 16 + erow + r;
                long col = tcol0 + (c >> 1) * 128 + wn * 32 + (c & 1) * 16 + ecol;
                float s = acc[a][c][r] * scale;
                if (ACT) s = s * s * 0.1f + s * 0.1f;
                C[row * N + col] = (CT)s;
            }
#undef PHASE_LO
#undef PHASE_HI
#undef STAGE_HT
}

// ---------------- 256x128 2-blocks/CU GEMM (double-barrier phases) -----------------
// 8 waves (4Mx2N), per-wave 64x64, BK=32, LDS 48KB.
// SWZ=0: 1-D grid (M/256)*(N/128), M%1024==0. SWZ=1: M==2048/batch. SWZ=2: M==1024.
template<int ACT, int SWZ, typename CT>
__global__ __launch_bounds__(512, 4) void gemm_bt_256x128(
    const bf16_t* __restrict__ A, const bf16_t* __restrict__ B, CT* __restrict__ C,
    int N, int K, long sA, long sB, long sC, float scale)
{
    __shared__ __align__(16) char smem[2 * 24576];   // 2 buf x (A 16KB + B 8KB)
    char* const sm = smem;

    const int bz = blockIdx.z;
    A += (long)bz * sA;  B += (long)bz * sB;  C += (long)bz * sC;

    const int lin = blockIdx.x;
    int tm, tn;
    if      (SWZ == 0) { const int xcd = lin & 7, jj = lin >> 3; tm = xcd * 4 + (jj & 3); tn = jj >> 2; }
    else if (SWZ == 1) { tm = lin & 7; tn = lin >> 3; }
    else               { tm = lin & 3; tn = lin >> 2; }
    const long trow0 = (long)tm * 256, tcol0 = (long)tn * 128;

    const int tid  = threadIdx.x;
    const int lane = tid & 63;
    const int wave = tid >> 6;
    const int wm = wave >> 1;
    const int wn = wave & 1;
    const int lr = lane & 15;
    const int ko2 = (lane >> 4) * 16;
    const int rbase = lr * 64 + (ko2 ^ (((lr >> 1) & 3) << 4));

    const int o0 = tid * 16;
    const int ol = o0 ^ (((o0 >> 7) & 3) << 4);
    const int sr = (ol >> 10) * 16 + ((ol >> 6) & 15);
    const int sc = (ol & 63) >> 1;

    const bf16_t* Abase = A + trow0 * K;
    const bf16_t* Bbase = B + tcol0 * K;

#define STAGE_A(kt, bufp) do {                                                        \
    gload_lds16(Abase + (long)sr * K         + ((kt) * 32 + sc), (bufp) + o0);        \
    gload_lds16(Abase + (long)(128 + sr) * K + ((kt) * 32 + sc), (bufp) + 8192 + o0); \
} while (0)
#define STAGE_B(kt, bufp) do {                                                        \
    gload_lds16(Bbase + (long)sr * K + ((kt) * 32 + sc), (bufp) + 16384 + o0);        \
} while (0)

    f32x4 acc[4][4];
#pragma unroll
    for (int i = 0; i < 4; ++i)
#pragma unroll
        for (int j = 0; j < 4; ++j)
            acc[i][j] = (f32x4){0.f, 0.f, 0.f, 0.f};

    STAGE_A(0, sm);
    STAGE_B(0, sm);
    STAGE_A(1, sm + 24576);
    asm volatile("s_waitcnt vmcnt(2)" ::: "memory");
    BAR();

    const int NT = K / 32;
    for (int t = 0; t < NT; ++t) {
        char* cur = sm + (t & 1) * 24576;
        char* idl = sm + ((t & 1) ^ 1) * 24576;

        // ---- P_LO: reads (A x4 + B-h0 x2) + stage B(t+1); BAR; lgkm0; 8 MFMA ---
        bf16x8 af_[4], bvA[2], bvB[2];
        af_[0] = *(const bf16x8*)(cur + (wm * 4 + 0) * 1024 + rbase);
        bvA[0] = *(const bf16x8*)(cur + 16384 + (wn * 2 + 0) * 1024 + rbase);
        bvA[1] = *(const bf16x8*)(cur + 16384 + (wn * 2 + 1) * 1024 + rbase);
#pragma unroll
        for (int i = 1; i < 4; ++i)
            af_[i] = *(const bf16x8*)(cur + (wm * 4 + i) * 1024 + rbase);
        if (t + 1 < NT) STAGE_B(t + 1, idl);
        BAR();
        LGKM0();
        __builtin_amdgcn_s_setprio(1);
#pragma unroll
        for (int i = 0; i < 4; ++i) {
            acc[i][0] = __builtin_amdgcn_mfma_f32_16x16x32_bf16(af_[i], bvA[0], acc[i][0], 0, 0, 0);
            acc[i][1] = __builtin_amdgcn_mfma_f32_16x16x32_bf16(af_[i], bvA[1], acc[i][1], 0, 0, 0);
        }
        __builtin_amdgcn_s_setprio(0);
        __builtin_amdgcn_sched_barrier(0);
        BAR();

        // ---- P_HI: reads B-h1 x2 (A reused in regs); stage A(t+2); BAR; MFMA ---
        bvB[0] = *(const bf16x8*)(cur + 16384 + (4 + wn * 2 + 0) * 1024 + rbase);
        bvB[1] = *(const bf16x8*)(cur + 16384 + (4 + wn * 2 + 1) * 1024 + rbase);
        if (t + 2 < NT) STAGE_A(t + 2, cur);
        BAR();
        LGKM0();
        __builtin_amdgcn_s_setprio(1);
#pragma unroll
        for (int i = 0; i < 4; ++i) {
            acc[i][2] = __builtin_amdgcn_mfma_f32_16x16x32_bf16(af_[i], bvB[0], acc[i][2], 0, 0, 0);
            acc[i][3] = __builtin_amdgcn_mfma_f32_16x16x32_bf16(af_[i], bvB[1], acc[i][3], 0, 0, 0);
        }
        __builtin_amdgcn_s_setprio(0);
        __builtin_amdgcn_sched_barrier(0);
        // producer-side: vmcnt(2) leaves only A(t+2)'s 2 loads -> B(t+1)/A(t+1)
        // landed before the barrier everyone reads them after.
        if (t + 2 < NT) { asm volatile("s_waitcnt vmcnt(2)" ::: "memory"); }
        else            { asm volatile("s_waitcnt vmcnt(0)" ::: "memory"); }
        BAR();
    }

    const int erow = (lane >> 4) * 4;
    const int ecol = lane & 15;
#pragma unroll
    for (int i = 0; i < 4; ++i)
#pragma unroll
        for (int j = 0; j < 4; ++j)
#pragma unroll
            for (int r = 0; r < 4; ++r) {
                long row = trow0 + wm * 64 + i * 16 + erow + r;
                long col = tcol0 + (j >> 1) * 64 + wn * 32 + (j & 1) * 16 + ecol;
                float s = acc[i][j][r] * scale;
                if (ACT) s = s * s * 0.1f + s * 0.1f;
                C[row * N + col] = (CT)s;
            }
#undef STAGE_A
#undef STAGE_B
}

// -----------------------------------------------------------------------------------
extern "C" void kernel_launch(void* const* d_in, const int* in_sizes, int n_in,
                              void* d_out, int out_size, void* d_ws, size_t ws_size,
                              hipStream_t stream) {
    const int*   x    = (const int*)d_in[0];
    const float* emb  = (const float*)d_in[1];
    const float* wq   = (const float*)d_in[2];
    const float* wk   = (const float*)d_in[3];
    const float* wv   = (const float*)d_in[4];
    const float* wo   = (const float*)d_in[5];
    const float* wout = (const float*)d_in[6];
    float* logits = (float*)d_out;

    char* ws = (char*)d_ws;
    size_t off = 0;
    auto alloc = [&](size_t bytes) {
        char* p = ws + off;
        off += (bytes + 255) & ~(size_t)255;
        return p;
    };
    bf16_t* hb    = (bf16_t*)alloc((size_t)BT * DIM * 2);
    bf16_t* qkb   = (bf16_t*)alloc((size_t)BT * 2 * DIM * 2);     // [8192, 2048] q|k
    bf16_t* vtb   = (bf16_t*)alloc((size_t)BATCH * DIM * SEQ * 2);
    bf16_t* attnb = (bf16_t*)alloc((size_t)BATCH * SEQ * SEQ * 2);
    bf16_t* o1b   = (bf16_t*)alloc((size_t)BT * DIM * 2);
    bf16_t* o2b   = (bf16_t*)alloc((size_t)BT * DIM * 2);
    bf16_t* wqkb  = (bf16_t*)alloc((size_t)2 * DIM * DIM * 2);    // [wq; wk] stacked
    bf16_t* wvb   = (bf16_t*)alloc((size_t)DIM * DIM * 2);
    bf16_t* wob   = (bf16_t*)alloc((size_t)DIM * DIM * 2);
    bf16_t* woutb = (bf16_t*)alloc((size_t)VOCAB * DIM * 2);

    {
        int n4 = DIM * DIM / 4;
        cast_f32_to_bf16<<<n4 / 256, 256, 0, stream>>>(wq, wqkb, n4);
        cast_f32_to_bf16<<<n4 / 256, 256, 0, stream>>>(wk, wqkb + (size_t)DIM * DIM, n4);
        cast_f32_to_bf16<<<n4 / 256, 256, 0, stream>>>(wv, wvb, n4);
        cast_f32_to_bf16<<<n4 / 256, 256, 0, stream>>>(wo, wob, n4);
        int n4o = VOCAB * DIM / 4;
        cast_f32_to_bf16<<<n4o / 256, 256, 0, stream>>>(wout, woutb, n4o);
    }

    embed_gather<<<BT, 256, 0, stream>>>(x, emb, hb);

    // fused q|k = 0.01 * h @ [wq;wk]^T -> qkb[8192,2048]; 512 blocks = 2/CU
    gemm_bt_256x128<0, 0, bf16_t><<<dim3((BT / 256) * (2 * DIM / 128), 1, 1), 512, 0, stream>>>(
        hb, wqkb, qkb, 2 * DIM, DIM, 0, 0, 0, 0.01f);

    // v^T[b] = 0.1 * wv @ h[b]^T: per-batch 4x16 = 64 blocks (SWZ=2)
    gemm_bt_256x128<0, 2, bf16_t><<<dim3(64, 1, BATCH), 512, 0, stream>>>(
        wvb, hb, vtb, SEQ, DIM, 0, (long)SEQ * DIM, (long)DIM * SEQ, 0.1f);

    // attn = fhe_act(0.01 * q[b] @ k[b]^T), q/k strided views of qkb (lda=2048)
    gemm_bt_256<1, 1, bf16_t><<<dim3(64, 1, BATCH), 512, 0, stream>>>(
        qkb, qkb + DIM, attnb, SEQ, DIM, 2 * DIM, 2 * DIM,
        (long)SEQ * 2 * DIM, (long)SEQ * 2 * DIM, (long)SEQ * SEQ, 0.01f);

    // o1 = 0.01 * attn[b] @ vT[b]^T: per-batch 8x8 = 64 blocks (SWZ=1), K=2048
    gemm_bt_256x128<0, 1, bf16_t><<<dim3(64, 1, BATCH), 512, 0, stream>>>(
        attnb, vtb, o1b, DIM, SEQ,
        (long)SEQ * SEQ, (long)DIM * SEQ, (long)SEQ * DIM, 0.01f);

    // o2 = 0.1 * o1 @ wo^T: 32x8 = 256 blocks (SWZ=0)
    gemm_bt_256x128<0, 0, bf16_t><<<dim3((BT / 256) * (DIM / 128), 1, 1), 512, 0, stream>>>(
        o1b, wob, o2b, DIM, DIM, 0, 0, 0, 0.1f);

    // logits = o2 @ wout^T: 32 * 250 = 8000 blocks, 2/CU
    gemm_bt_256x128<0, 0, float><<<dim3((BT / 256) * (VOCAB / 128), 1, 1), 512, 0, stream>>>(
        o2b, woutb, logits, VOCAB, DIM, 0, 0, 0, 1.0f);
}

// Round 17
// 881.541 us; speedup vs baseline: 1.0109x; 1.0109x over previous
//
#include <hip/hip_runtime.h>

// FHETinyGPT forward. R17: 256x128 kernel consolidated to ONE phase per K-tile
// (reads A4+B4, one lgkm wait, one 16-MFMA cluster, 2 barriers) using a 3rd LDS
// buffer (72KB, still 2 blocks/CU): stage target (t+2)%3 was last read at tile
// t-1 (sealed by its closing barrier) -> no WAR race that forced the 2-phase
// split with 2 buffers. Counted vmcnt(3) never drains in steady state (tile t+1
// landed = all-but-3). Halves lgkm-stall points vs R15. QK^T kernel = R15 exact
// (R16's double-barrier variant regressed; reverted).
// Plateau ledger: 38% MfmaUtil survived single/double-barrier, 1/2 blocks-CU,
// 0.75/0.5/0.375 reads-per-MFMA, BK 32/64 -> this tests sync-section count.

typedef __bf16 bf16_t;
typedef __bf16 bf16x8 __attribute__((ext_vector_type(8)));
typedef __bf16 bf16x4 __attribute__((ext_vector_type(4)));
typedef float  f32x4  __attribute__((ext_vector_type(4)));

#define VOCAB 32000
#define DIM   1024
#define BATCH 4
#define SEQ   2048
#define BT    (BATCH*SEQ)   // 8192

__device__ __forceinline__ void gload_lds16(const void* g, void* l) {
    __builtin_amdgcn_global_load_lds(
        (const __attribute__((address_space(1))) void*)g,
        (__attribute__((address_space(3))) void*)l,
        16, 0, 0);
}

// ---------------- weight cast f32 -> bf16 ------------------------------------------
__global__ void cast_f32_to_bf16(const float* __restrict__ in, bf16_t* __restrict__ out, int n4) {
    int i = blockIdx.x * blockDim.x + threadIdx.x;
    if (i < n4) {
        float4 v = ((const float4*)in)[i];
        bf16x4 o;
        o.x = (bf16_t)v.x; o.y = (bf16_t)v.y; o.z = (bf16_t)v.z; o.w = (bf16_t)v.w;
        ((bf16x4*)out)[i] = o;
    }
}

// ---------------- h = emb_w[x] * 0.01 -> bf16 [BT, DIM] ----------------------------
__global__ void embed_gather(const int* __restrict__ x, const float* __restrict__ emb,
                             bf16_t* __restrict__ h) {
    const int tok = blockIdx.x;
    const int row = x[tok];
    const float4* src = (const float4*)(emb + (long)row * DIM);
    bf16x4* dst = (bf16x4*)(h + (long)tok * DIM);
    int j = threadIdx.x;
    float4 v = src[j];
    bf16x4 o;
    o.x = (bf16_t)(v.x * 0.01f); o.y = (bf16_t)(v.y * 0.01f);
    o.z = (bf16_t)(v.z * 0.01f); o.w = (bf16_t)(v.w * 0.01f);
    dst[j] = o;
}

#define BAR() asm volatile("s_barrier" ::: "memory")
#define LGKM0() do { asm volatile("s_waitcnt lgkmcnt(0)" ::: "memory");               \
                     __builtin_amdgcn_sched_barrier(0); } while (0)

// ---------------- 256x256 pipelined GEMM (R15 form) with lda/ldb -------------------
// C[M,N] = epi(scale * A[M,K] @ B[N,K]^T); SWZ=1: grid (64,1,BATCH), M==N==2048.
template<int ACT, int SWZ, typename CT>
__global__ __launch_bounds__(512, 2) void gemm_bt_256(
    const bf16_t* __restrict__ A, const bf16_t* __restrict__ B, CT* __restrict__ C,
    int N, int K, int lda, int ldb, long sA, long sB, long sC, float scale)
{
    __shared__ __align__(16) char smem[131072];   // 2buf x (A 32KB + B 32KB)
    char* const sm = smem;

    const int bz = blockIdx.z;
    A += (long)bz * sA;  B += (long)bz * sB;  C += (long)bz * sC;

    const int lin = blockIdx.x;
    int tm, tn;
    if (SWZ == 0) { const int xcd = lin & 7, jj = lin >> 3; tm = xcd * 4 + (jj & 3); tn = jj >> 2; }
    else          { tm = lin & 7; tn = lin >> 3; }
    const long trow0 = (long)tm * 256, tcol0 = (long)tn * 256;

    const int tid  = threadIdx.x;
    const int lane = tid & 63;
    const int wave = tid >> 6;
    const int wm = wave >> 2;
    const int wn = wave & 3;
    const int lr = lane & 15;
    const int ko2 = (lane >> 4) * 16;
    const int rbase = lr * 64 + (ko2 ^ (((lr >> 1) & 3) << 4));

    const int o0 = tid * 16, o1 = 8192 + tid * 16;
    int sr0, sc0, sr1, sc1;
    {
        int ol = o0 ^ (((o0 >> 7) & 3) << 4);
        sr0 = ((ol >> 10) >> 1) * 16 + ((ol >> 6) & 15);
        sc0 = ((ol >> 10) & 1) * 32 + ((ol & 63) >> 1);
        ol = o1 ^ (((o1 >> 7) & 3) << 4);
        sr1 = ((ol >> 10) >> 1) * 16 + ((ol >> 6) & 15);
        sc1 = ((ol >> 10) & 1) * 32 + ((ol & 63) >> 1);
    }

    const bf16_t* Abase = A + trow0 * lda;
    const bf16_t* Bbase = B + tcol0 * ldb;

#define STAGE_HT(gbase, ld, kt, half, ldsh) do {                                      \
    gload_lds16((gbase) + (long)((half) * 128 + sr0) * (ld) + ((kt) * 64 + sc0), (ldsh) + o0); \
    gload_lds16((gbase) + (long)((half) * 128 + sr1) * (ld) + ((kt) * 64 + sc1), (ldsh) + o1); \
} while (0)

    f32x4 acc[8][4];
#pragma unroll
    for (int i = 0; i < 8; ++i)
#pragma unroll
        for (int j = 0; j < 4; ++j)
            acc[i][j] = (f32x4){0.f, 0.f, 0.f, 0.f};

#define PHASE_LO(ks, ...) do {                                                        \
    bf16x8 af_[4];                                                                    \
    af_[0] = *(const bf16x8*)(ldsA + ((wm * 4 + 0) * 2 + (ks)) * 1024 + rbase);       \
    _Pragma("unroll")                                                                 \
    for (int c_ = 0; c_ < 4; ++c_)                                                    \
        bv_[c_] = *(const bf16x8*)(ldsB + (c_ >> 1) * 16384 +                         \
                      ((wn * 2 + (c_ & 1)) * 2 + (ks)) * 1024 + rbase);               \
    _Pragma("unroll")                                                                 \
    for (int i_ = 1; i_ < 4; ++i_)                                                    \
        af_[i_] = *(const bf16x8*)(ldsA +                                             \
                      ((wm * 4 + i_) * 2 + (ks)) * 1024 + rbase);                     \
    __VA_ARGS__;                                                                      \
    __builtin_amdgcn_s_setprio(1);                                                    \
    _Pragma("unroll")                                                                 \
    for (int i_ = 0; i_ < 4; ++i_)                                                    \
        _Pragma("unroll")                                                             \
        for (int c_ = 0; c_ < 4; ++c_)                                                \
            acc[i_][c_] = __builtin_amdgcn_mfma_f32_16x16x32_bf16(                    \
                af_[i_], bv_[c_], acc[i_][c_], 0, 0, 0);                              \
    __builtin_amdgcn_s_setprio(0);                                                    \
    __builtin_amdgcn_sched_barrier(0);                                                \
    BAR();                                                                            \
} while (0)

#define PHASE_HI(ks, ...) do {                                                        \
    bf16x8 af_[4];                                                                    \
    _Pragma("unroll")                                                                 \
    for (int i_ = 0; i_ < 4; ++i_)                                                    \
        af_[i_] = *(const bf16x8*)(ldsA + 16384 +                                     \
                      ((wm * 4 + i_) * 2 + (ks)) * 1024 + rbase);                     \
    __VA_ARGS__;                                                                      \
    __builtin_amdgcn_s_setprio(1);                                                    \
    _Pragma("unroll")                                                                 \
    for (int i_ = 0; i_ < 4; ++i_)                                                    \
        _Pragma("unroll")                                                             \
        for (int c_ = 0; c_ < 4; ++c_)                                                \
            acc[4 + i_][c_] = __builtin_amdgcn_mfma_f32_16x16x32_bf16(                \
                af_[i_], bv_[c_], acc[4 + i_][c_], 0, 0, 0);                          \
    __builtin_amdgcn_s_setprio(0);                                                    \
    __builtin_amdgcn_sched_barrier(0);                                                \
} while (0)

    {
        char* a0 = sm;
        char* b0 = sm + 32768;
        char* a1 = sm + 65536;
        char* b1 = sm + 65536 + 32768;
        STAGE_HT(Abase, lda, 0, 0, a0);
        STAGE_HT(Bbase, ldb, 0, 0, b0);
        STAGE_HT(Abase, lda, 0, 1, a0 + 16384);
        STAGE_HT(Bbase, ldb, 0, 1, b0 + 16384);
        STAGE_HT(Abase, lda, 1, 0, a1);
        STAGE_HT(Bbase, ldb, 1, 0, b1);
        asm volatile("s_waitcnt vmcnt(4)" ::: "memory");
        BAR();
    }

    const int NT = K / 64;
    for (int t = 0; t < NT; ++t) {
        const int buf = t & 1;
        char* ldsA  = sm + buf * 65536;
        char* ldsB  = ldsA + 32768;
        char* ldsAn = sm + (buf ^ 1) * 65536;
        char* ldsBn = ldsAn + 32768;
        bf16x8 bv_[4];

        PHASE_LO(0,
              if (t + 1 < NT) {
                  STAGE_HT(Abase, lda, t + 1, 1, ldsAn + 16384);
                  STAGE_HT(Bbase, ldb, t + 1, 1, ldsBn + 16384);
              });
        PHASE_HI(0, );
        BAR();
        PHASE_LO(1, );
        PHASE_HI(1,
              if (t + 2 < NT) {
                  STAGE_HT(Abase, lda, t + 2, 0, ldsA);
                  STAGE_HT(Bbase, ldb, t + 2, 0, ldsB);
              });
        if (t + 2 < NT) { asm volatile("s_waitcnt vmcnt(4)" ::: "memory"); }
        else            { asm volatile("s_waitcnt vmcnt(0)" ::: "memory"); }
        BAR();
    }

    const int erow = (lane >> 4) * 4;
    const int ecol = lane & 15;
#pragma unroll
    for (int a = 0; a < 8; ++a)
#pragma unroll
        for (int c = 0; c < 4; ++c)
#pragma unroll
            for (int r = 0; r < 4; ++r) {
                long row = trow0 + (a >> 2) * 128 + wm * 64 + (a & 3) * 16 + erow + r;
                long col = tcol0 + (c >> 1) * 128 + wn * 32 + (c & 1) * 16 + ecol;
                float s = acc[a][c][r] * scale;
                if (ACT) s = s * s * 0.1f + s * 0.1f;
                C[row * N + col] = (CT)s;
            }
#undef PHASE_LO
#undef PHASE_HI
#undef STAGE_HT
}

// ---------------- 256x128 GEMM, ONE phase per K-tile, 3 LDS buffers ----------------
// 8 waves (4Mx2N), per-wave 64x64, BK=32, LDS 72KB, 2 blocks/CU.
// Per tile: {read A4+B4 from buf t%3; stage tile t+2 -> buf (t+2)%3; BAR; lgkm0;
// 16 MFMA; vmcnt(3) [tail 0]; BAR}. Buffer (t+2)%3 last read at tile t-1, sealed
// by its closing barrier -> stage-write WAR-safe. vmcnt(3) at tile end => oldest
// 3 (tile t+1's stages) landed before the barrier all waves read them after.
// SWZ=0: 1-D grid (M/256)*(N/128), M%1024==0. SWZ=1: M==2048/batch. SWZ=2: M==1024.
template<int ACT, int SWZ, typename CT>
__global__ __launch_bounds__(512, 4) void gemm_bt_256x128(
    const bf16_t* __restrict__ A, const bf16_t* __restrict__ B, CT* __restrict__ C,
    int N, int K, long sA, long sB, long sC, float scale)
{
    __shared__ __align__(16) char smem[3 * 24576];   // 3 buf x (A 16KB + B 8KB)
    char* const sm = smem;

    const int bz = blockIdx.z;
    A += (long)bz * sA;  B += (long)bz * sB;  C += (long)bz * sC;

    const int lin = blockIdx.x;
    int tm, tn;
    if      (SWZ == 0) { const int xcd = lin & 7, jj = lin >> 3; tm = xcd * 4 + (jj & 3); tn = jj >> 2; }
    else if (SWZ == 1) { tm = lin & 7; tn = lin >> 3; }
    else               { tm = lin & 3; tn = lin >> 2; }
    const long trow0 = (long)tm * 256, tcol0 = (long)tn * 128;

    const int tid  = threadIdx.x;
    const int lane = tid & 63;
    const int wave = tid >> 6;
    const int wm = wave >> 1;
    const int wn = wave & 1;
    const int lr = lane & 15;
    const int ko2 = (lane >> 4) * 16;
    const int rbase = lr * 64 + (ko2 ^ (((lr >> 1) & 3) << 4));

    const int o0 = tid * 16;
    const int ol = o0 ^ (((o0 >> 7) & 3) << 4);
    const int sr = (ol >> 10) * 16 + ((ol >> 6) & 15);
    const int sc = (ol & 63) >> 1;

    const bf16_t* Abase = A + trow0 * K;
    const bf16_t* Bbase = B + tcol0 * K;

#define STAGE_A(kt, bufp) do {                                                        \
    gload_lds16(Abase + (long)sr * K         + ((kt) * 32 + sc), (bufp) + o0);        \
    gload_lds16(Abase + (long)(128 + sr) * K + ((kt) * 32 + sc), (bufp) + 8192 + o0); \
} while (0)
#define STAGE_B(kt, bufp) do {                                                        \
    gload_lds16(Bbase + (long)sr * K + ((kt) * 32 + sc), (bufp) + 16384 + o0);        \
} while (0)

    f32x4 acc[4][4];
#pragma unroll
    for (int i = 0; i < 4; ++i)
#pragma unroll
        for (int j = 0; j < 4; ++j)
            acc[i][j] = (f32x4){0.f, 0.f, 0.f, 0.f};

    // prologue: tiles 0,1 staged (3 loads each); vmcnt(3) => tile 0 landed.
    STAGE_A(0, sm);             STAGE_B(0, sm);
    STAGE_A(1, sm + 24576);     STAGE_B(1, sm + 24576);
    asm volatile("s_waitcnt vmcnt(3)" ::: "memory");
    BAR();

    const int NT = K / 32;
    int bi = 0;                  // t % 3
    for (int t = 0; t < NT; ++t) {
        char* cur = sm + bi * 24576;
        const int bn = (bi + 2 >= 3) ? bi - 1 : bi + 2;   // (t+2) % 3
        char* nxt = sm + bn * 24576;

        // reads (fly during the barrier wait) + next-next tile stage
        bf16x8 af_[4], bv_[4];
        af_[0] = *(const bf16x8*)(cur + (wm * 4 + 0) * 1024 + rbase);
        bv_[0] = *(const bf16x8*)(cur + 16384 + (wn * 2 + 0) * 1024 + rbase);
        bv_[1] = *(const bf16x8*)(cur + 16384 + (wn * 2 + 1) * 1024 + rbase);
#pragma unroll
        for (int i = 1; i < 4; ++i)
            af_[i] = *(const bf16x8*)(cur + (wm * 4 + i) * 1024 + rbase);
        bv_[2] = *(const bf16x8*)(cur + 16384 + (4 + wn * 2 + 0) * 1024 + rbase);
        bv_[3] = *(const bf16x8*)(cur + 16384 + (4 + wn * 2 + 1) * 1024 + rbase);
        if (t + 2 < NT) { STAGE_A(t + 2, nxt); STAGE_B(t + 2, nxt); }
        BAR();
        LGKM0();
        __builtin_amdgcn_s_setprio(1);
#pragma unroll
        for (int i = 0; i < 4; ++i)
#pragma unroll
            for (int j = 0; j < 4; ++j)
                acc[i][j] = __builtin_amdgcn_mfma_f32_16x16x32_bf16(
                    af_[i], bv_[j], acc[i][j], 0, 0, 0);
        __builtin_amdgcn_s_setprio(0);
        __builtin_amdgcn_sched_barrier(0);
        // producer-side: oldest 3 outstanding = tile t+1's stages -> landed.
        if (t + 2 < NT) { asm volatile("s_waitcnt vmcnt(3)" ::: "memory"); }
        else            { asm volatile("s_waitcnt vmcnt(0)" ::: "memory"); }
        BAR();
        bi = (bi == 2) ? 0 : bi + 1;
    }

    const int erow = (lane >> 4) * 4;
    const int ecol = lane & 15;
#pragma unroll
    for (int i = 0; i < 4; ++i)
#pragma unroll
        for (int j = 0; j < 4; ++j)
#pragma unroll
            for (int r = 0; r < 4; ++r) {
                long row = trow0 + wm * 64 + i * 16 + erow + r;
                long col = tcol0 + (j >> 1) * 64 + wn * 32 + (j & 1) * 16 + ecol;
                float s = acc[i][j][r] * scale;
                if (ACT) s = s * s * 0.1f + s * 0.1f;
                C[row * N + col] = (CT)s;
            }
#undef STAGE_A
#undef STAGE_B
}

// -----------------------------------------------------------------------------------
extern "C" void kernel_launch(void* const* d_in, const int* in_sizes, int n_in,
                              void* d_out, int out_size, void* d_ws, size_t ws_size,
                              hipStream_t stream) {
    const int*   x    = (const int*)d_in[0];
    const float* emb  = (const float*)d_in[1];
    const float* wq   = (const float*)d_in[2];
    const float* wk   = (const float*)d_in[3];
    const float* wv   = (const float*)d_in[4];
    const float* wo   = (const float*)d_in[5];
    const float* wout = (const float*)d_in[6];
    float* logits = (float*)d_out;

    char* ws = (char*)d_ws;
    size_t off = 0;
    auto alloc = [&](size_t bytes) {
        char* p = ws + off;
        off += (bytes + 255) & ~(size_t)255;
        return p;
    };
    bf16_t* hb    = (bf16_t*)alloc((size_t)BT * DIM * 2);
    bf16_t* qkb   = (bf16_t*)alloc((size_t)BT * 2 * DIM * 2);     // [8192, 2048] q|k
    bf16_t* vtb   = (bf16_t*)alloc((size_t)BATCH * DIM * SEQ * 2);
    bf16_t* attnb = (bf16_t*)alloc((size_t)BATCH * SEQ * SEQ * 2);
    bf16_t* o1b   = (bf16_t*)alloc((size_t)BT * DIM * 2);
    bf16_t* o2b   = (bf16_t*)alloc((size_t)BT * DIM * 2);
    bf16_t* wqkb  = (bf16_t*)alloc((size_t)2 * DIM * DIM * 2);    // [wq; wk] stacked
    bf16_t* wvb   = (bf16_t*)alloc((size_t)DIM * DIM * 2);
    bf16_t* wob   = (bf16_t*)alloc((size_t)DIM * DIM * 2);
    bf16_t* woutb = (bf16_t*)alloc((size_t)VOCAB * DIM * 2);

    {
        int n4 = DIM * DIM / 4;
        cast_f32_to_bf16<<<n4 / 256, 256, 0, stream>>>(wq, wqkb, n4);
        cast_f32_to_bf16<<<n4 / 256, 256, 0, stream>>>(wk, wqkb + (size_t)DIM * DIM, n4);
        cast_f32_to_bf16<<<n4 / 256, 256, 0, stream>>>(wv, wvb, n4);
        cast_f32_to_bf16<<<n4 / 256, 256, 0, stream>>>(wo, wob, n4);
        int n4o = VOCAB * DIM / 4;
        cast_f32_to_bf16<<<n4o / 256, 256, 0, stream>>>(wout, woutb, n4o);
    }

    embed_gather<<<BT, 256, 0, stream>>>(x, emb, hb);

    // fused q|k = 0.01 * h @ [wq;wk]^T -> qkb[8192,2048]; 512 blocks = 2/CU
    gemm_bt_256x128<0, 0, bf16_t><<<dim3((BT / 256) * (2 * DIM / 128), 1, 1), 512, 0, stream>>>(
        hb, wqkb, qkb, 2 * DIM, DIM, 0, 0, 0, 0.01f);

    // v^T[b] = 0.1 * wv @ h[b]^T: per-batch 4x16 = 64 blocks (SWZ=2)
    gemm_bt_256x128<0, 2, bf16_t><<<dim3(64, 1, BATCH), 512, 0, stream>>>(
        wvb, hb, vtb, SEQ, DIM, 0, (long)SEQ * DIM, (long)DIM * SEQ, 0.1f);

    // attn = fhe_act(0.01 * q[b] @ k[b]^T), q/k strided views of qkb (lda=2048)
    gemm_bt_256<1, 1, bf16_t><<<dim3(64, 1, BATCH), 512, 0, stream>>>(
        qkb, qkb + DIM, attnb, SEQ, DIM, 2 * DIM, 2 * DIM,
        (long)SEQ * 2 * DIM, (long)SEQ * 2 * DIM, (long)SEQ * SEQ, 0.01f);

    // o1 = 0.01 * attn[b] @ vT[b]^T: per-batch 8x8 = 64 blocks (SWZ=1), K=2048
    gemm_bt_256x128<0, 1, bf16_t><<<dim3(64, 1, BATCH), 512, 0, stream>>>(
        attnb, vtb, o1b, DIM, SEQ,
        (long)SEQ * SEQ, (long)DIM * SEQ, (long)SEQ * DIM, 0.01f);

    // o2 = 0.1 * o1 @ wo^T: 32x8 = 256 blocks (SWZ=0)
    gemm_bt_256x128<0, 0, bf16_t><<<dim3((BT / 256) * (DIM / 128), 1, 1), 512, 0, stream>>>(
        o1b, wob, o2b, DIM, DIM, 0, 0, 0, 0.1f);

    // logits = o2 @ wout^T: 32 * 250 = 8000 blocks, 2/CU
    gemm_bt_256x128<0, 0, float><<<dim3((BT / 256) * (VOCAB / 128), 1, 1), 512, 0, stream>>>(
        o2b, woutb, logits, VOCAB, DIM, 0, 0, 0, 1.0f);
}

// Round 18
// 877.997 us; speedup vs baseline: 1.0150x; 1.0040x over previous
//
#include <hip/hip_runtime.h>

// FHETinyGPT forward — converged state (R18).
// Pipeline: batched-cast -> embed -> fused q|k GEMM -> vT GEMM -> QK^T(+poly act)
//           -> PV -> o2 -> logits. All matmuls bf16 MFMA, two kernel structures:
//  - gemm_bt_256   (256^2, BK=64, 1 blk/CU): QK^T (R12-proven best at M=N=2048).
//  - gemm_bt_256x128 (256x128, BK=32, 3-buf single-phase, 2 blk/CU): the rest.
// Plateau ledger (R4-R17): MfmaUtil ~38% invariant across phase count 1/2/4,
// single/double barrier, 2/3 LDS buffers, 1/2 blocks/CU, 0.75/0.5/0.375
// reads/MFMA, BK 32/64; ILP ping-pong spills (R9-11), TLP null (R13).
// Structural constraint: K=1024 cannot amortize per-block fixed costs the way
// m201's 62% does at K=4096. Total sits ~6% above the demonstrated-throughput
// floor (674 GF @ 853 TF + casts/embed).
// R18: merged the 4 DIM^2 weight casts into one dispatch (launch overhead only).

typedef __bf16 bf16_t;
typedef __bf16 bf16x8 __attribute__((ext_vector_type(8)));
typedef __bf16 bf16x4 __attribute__((ext_vector_type(4)));
typedef float  f32x4  __attribute__((ext_vector_type(4)));

#define VOCAB 32000
#define DIM   1024
#define BATCH 4
#define SEQ   2048
#define BT    (BATCH*SEQ)   // 8192

__device__ __forceinline__ void gload_lds16(const void* g, void* l) {
    __builtin_amdgcn_global_load_lds(
        (const __attribute__((address_space(1))) void*)g,
        (__attribute__((address_space(3))) void*)l,
        16, 0, 0);
}

// ---------------- weight casts f32 -> bf16 -----------------------------------------
__global__ void cast_f32_to_bf16(const float* __restrict__ in, bf16_t* __restrict__ out, int n4) {
    int i = blockIdx.x * blockDim.x + threadIdx.x;
    if (i < n4) {
        float4 v = ((const float4*)in)[i];
        bf16x4 o;
        o.x = (bf16_t)v.x; o.y = (bf16_t)v.y; o.z = (bf16_t)v.z; o.w = (bf16_t)v.w;
        ((bf16x4*)out)[i] = o;
    }
}

// 4 same-size casts in one dispatch (blockIdx.y selects tensor)
__global__ void cast4_f32_to_bf16(const float* __restrict__ s0, const float* __restrict__ s1,
                                  const float* __restrict__ s2, const float* __restrict__ s3,
                                  bf16_t* __restrict__ d0, bf16_t* __restrict__ d1,
                                  bf16_t* __restrict__ d2, bf16_t* __restrict__ d3, int n4) {
    const float* src = (blockIdx.y == 0) ? s0 : (blockIdx.y == 1) ? s1 : (blockIdx.y == 2) ? s2 : s3;
    bf16_t*      dst = (blockIdx.y == 0) ? d0 : (blockIdx.y == 1) ? d1 : (blockIdx.y == 2) ? d2 : d3;
    int i = blockIdx.x * blockDim.x + threadIdx.x;
    if (i < n4) {
        float4 v = ((const float4*)src)[i];
        bf16x4 o;
        o.x = (bf16_t)v.x; o.y = (bf16_t)v.y; o.z = (bf16_t)v.z; o.w = (bf16_t)v.w;
        ((bf16x4*)dst)[i] = o;
    }
}

// ---------------- h = emb_w[x] * 0.01 -> bf16 [BT, DIM] ----------------------------
__global__ void embed_gather(const int* __restrict__ x, const float* __restrict__ emb,
                             bf16_t* __restrict__ h) {
    const int tok = blockIdx.x;
    const int row = x[tok];
    const float4* src = (const float4*)(emb + (long)row * DIM);
    bf16x4* dst = (bf16x4*)(h + (long)tok * DIM);
    int j = threadIdx.x;
    float4 v = src[j];
    bf16x4 o;
    o.x = (bf16_t)(v.x * 0.01f); o.y = (bf16_t)(v.y * 0.01f);
    o.z = (bf16_t)(v.z * 0.01f); o.w = (bf16_t)(v.w * 0.01f);
    dst[j] = o;
}

#define BAR() asm volatile("s_barrier" ::: "memory")
#define LGKM0() do { asm volatile("s_waitcnt lgkmcnt(0)" ::: "memory");               \
                     __builtin_amdgcn_sched_barrier(0); } while (0)

// ---------------- 256x256 pipelined GEMM (R15 form) with lda/ldb -------------------
// C[M,N] = epi(scale * A[M,K] @ B[N,K]^T); SWZ=1: grid (64,1,BATCH), M==N==2048.
template<int ACT, int SWZ, typename CT>
__global__ __launch_bounds__(512, 2) void gemm_bt_256(
    const bf16_t* __restrict__ A, const bf16_t* __restrict__ B, CT* __restrict__ C,
    int N, int K, int lda, int ldb, long sA, long sB, long sC, float scale)
{
    __shared__ __align__(16) char smem[131072];   // 2buf x (A 32KB + B 32KB)
    char* const sm = smem;

    const int bz = blockIdx.z;
    A += (long)bz * sA;  B += (long)bz * sB;  C += (long)bz * sC;

    const int lin = blockIdx.x;
    int tm, tn;
    if (SWZ == 0) { const int xcd = lin & 7, jj = lin >> 3; tm = xcd * 4 + (jj & 3); tn = jj >> 2; }
    else          { tm = lin & 7; tn = lin >> 3; }
    const long trow0 = (long)tm * 256, tcol0 = (long)tn * 256;

    const int tid  = threadIdx.x;
    const int lane = tid & 63;
    const int wave = tid >> 6;
    const int wm = wave >> 2;
    const int wn = wave & 3;
    const int lr = lane & 15;
    const int ko2 = (lane >> 4) * 16;
    const int rbase = lr * 64 + (ko2 ^ (((lr >> 1) & 3) << 4));

    const int o0 = tid * 16, o1 = 8192 + tid * 16;
    int sr0, sc0, sr1, sc1;
    {
        int ol = o0 ^ (((o0 >> 7) & 3) << 4);
        sr0 = ((ol >> 10) >> 1) * 16 + ((ol >> 6) & 15);
        sc0 = ((ol >> 10) & 1) * 32 + ((ol & 63) >> 1);
        ol = o1 ^ (((o1 >> 7) & 3) << 4);
        sr1 = ((ol >> 10) >> 1) * 16 + ((ol >> 6) & 15);
        sc1 = ((ol >> 10) & 1) * 32 + ((ol & 63) >> 1);
    }

    const bf16_t* Abase = A + trow0 * lda;
    const bf16_t* Bbase = B + tcol0 * ldb;

#define STAGE_HT(gbase, ld, kt, half, ldsh) do {                                      \
    gload_lds16((gbase) + (long)((half) * 128 + sr0) * (ld) + ((kt) * 64 + sc0), (ldsh) + o0); \
    gload_lds16((gbase) + (long)((half) * 128 + sr1) * (ld) + ((kt) * 64 + sc1), (ldsh) + o1); \
} while (0)

    f32x4 acc[8][4];
#pragma unroll
    for (int i = 0; i < 8; ++i)
#pragma unroll
        for (int j = 0; j < 4; ++j)
            acc[i][j] = (f32x4){0.f, 0.f, 0.f, 0.f};

#define PHASE_LO(ks, ...) do {                                                        \
    bf16x8 af_[4];                                                                    \
    af_[0] = *(const bf16x8*)(ldsA + ((wm * 4 + 0) * 2 + (ks)) * 1024 + rbase);       \
    _Pragma("unroll")                                                                 \
    for (int c_ = 0; c_ < 4; ++c_)                                                    \
        bv_[c_] = *(const bf16x8*)(ldsB + (c_ >> 1) * 16384 +                         \
                      ((wn * 2 + (c_ & 1)) * 2 + (ks)) * 1024 + rbase);               \
    _Pragma("unroll")                                                                 \
    for (int i_ = 1; i_ < 4; ++i_)                                                    \
        af_[i_] = *(const bf16x8*)(ldsA +                                             \
                      ((wm * 4 + i_) * 2 + (ks)) * 1024 + rbase);                     \
    __VA_ARGS__;                                                                      \
    __builtin_amdgcn_s_setprio(1);                                                    \
    _Pragma("unroll")                                                                 \
    for (int i_ = 0; i_ < 4; ++i_)                                                    \
        _Pragma("unroll")                                                             \
        for (int c_ = 0; c_ < 4; ++c_)                                                \
            acc[i_][c_] = __builtin_amdgcn_mfma_f32_16x16x32_bf16(                    \
                af_[i_], bv_[c_], acc[i_][c_], 0, 0, 0);                              \
    __builtin_amdgcn_s_setprio(0);                                                    \
    __builtin_amdgcn_sched_barrier(0);                                                \
    BAR();                                                                            \
} while (0)

#define PHASE_HI(ks, ...) do {                                                        \
    bf16x8 af_[4];                                                                    \
    _Pragma("unroll")                                                                 \
    for (int i_ = 0; i_ < 4; ++i_)                                                    \
        af_[i_] = *(const bf16x8*)(ldsA + 16384 +                                     \
                      ((wm * 4 + i_) * 2 + (ks)) * 1024 + rbase);                     \
    __VA_ARGS__;                                                                      \
    __builtin_amdgcn_s_setprio(1);                                                    \
    _Pragma("unroll")                                                                 \
    for (int i_ = 0; i_ < 4; ++i_)                                                    \
        _Pragma("unroll")                                                             \
        for (int c_ = 0; c_ < 4; ++c_)                                                \
            acc[4 + i_][c_] = __builtin_amdgcn_mfma_f32_16x16x32_bf16(                \
                af_[i_], bv_[c_], acc[4 + i_][c_], 0, 0, 0);                          \
    __builtin_amdgcn_s_setprio(0);                                                    \
    __builtin_amdgcn_sched_barrier(0);                                                \
} while (0)

    {
        char* a0 = sm;
        char* b0 = sm + 32768;
        char* a1 = sm + 65536;
        char* b1 = sm + 65536 + 32768;
        STAGE_HT(Abase, lda, 0, 0, a0);
        STAGE_HT(Bbase, ldb, 0, 0, b0);
        STAGE_HT(Abase, lda, 0, 1, a0 + 16384);
        STAGE_HT(Bbase, ldb, 0, 1, b0 + 16384);
        STAGE_HT(Abase, lda, 1, 0, a1);
        STAGE_HT(Bbase, ldb, 1, 0, b1);
        asm volatile("s_waitcnt vmcnt(4)" ::: "memory");
        BAR();
    }

    const int NT = K / 64;
    for (int t = 0; t < NT; ++t) {
        const int buf = t & 1;
        char* ldsA  = sm + buf * 65536;
        char* ldsB  = ldsA + 32768;
        char* ldsAn = sm + (buf ^ 1) * 65536;
        char* ldsBn = ldsAn + 32768;
        bf16x8 bv_[4];

        PHASE_LO(0,
              if (t + 1 < NT) {
                  STAGE_HT(Abase, lda, t + 1, 1, ldsAn + 16384);
                  STAGE_HT(Bbase, ldb, t + 1, 1, ldsBn + 16384);
              });
        PHASE_HI(0, );
        BAR();
        PHASE_LO(1, );
        PHASE_HI(1,
              if (t + 2 < NT) {
                  STAGE_HT(Abase, lda, t + 2, 0, ldsA);
                  STAGE_HT(Bbase, ldb, t + 2, 0, ldsB);
              });
        if (t + 2 < NT) { asm volatile("s_waitcnt vmcnt(4)" ::: "memory"); }
        else            { asm volatile("s_waitcnt vmcnt(0)" ::: "memory"); }
        BAR();
    }

    const int erow = (lane >> 4) * 4;
    const int ecol = lane & 15;
#pragma unroll
    for (int a = 0; a < 8; ++a)
#pragma unroll
        for (int c = 0; c < 4; ++c)
#pragma unroll
            for (int r = 0; r < 4; ++r) {
                long row = trow0 + (a >> 2) * 128 + wm * 64 + (a & 3) * 16 + erow + r;
                long col = tcol0 + (c >> 1) * 128 + wn * 32 + (c & 1) * 16 + ecol;
                float s = acc[a][c][r] * scale;
                if (ACT) s = s * s * 0.1f + s * 0.1f;
                C[row * N + col] = (CT)s;
            }
#undef PHASE_LO
#undef PHASE_HI
#undef STAGE_HT
}

// ---------------- 256x128 GEMM, ONE phase per K-tile, 3 LDS buffers (R17) ----------
// 8 waves (4Mx2N), per-wave 64x64, BK=32, LDS 72KB, 2 blocks/CU.
// SWZ=0: 1-D grid (M/256)*(N/128), M%1024==0. SWZ=1: M==2048/batch. SWZ=2: M==1024.
template<int ACT, int SWZ, typename CT>
__global__ __launch_bounds__(512, 4) void gemm_bt_256x128(
    const bf16_t* __restrict__ A, const bf16_t* __restrict__ B, CT* __restrict__ C,
    int N, int K, long sA, long sB, long sC, float scale)
{
    __shared__ __align__(16) char smem[3 * 24576];   // 3 buf x (A 16KB + B 8KB)
    char* const sm = smem;

    const int bz = blockIdx.z;
    A += (long)bz * sA;  B += (long)bz * sB;  C += (long)bz * sC;

    const int lin = blockIdx.x;
    int tm, tn;
    if      (SWZ == 0) { const int xcd = lin & 7, jj = lin >> 3; tm = xcd * 4 + (jj & 3); tn = jj >> 2; }
    else if (SWZ == 1) { tm = lin & 7; tn = lin >> 3; }
    else               { tm = lin & 3; tn = lin >> 2; }
    const long trow0 = (long)tm * 256, tcol0 = (long)tn * 128;

    const int tid  = threadIdx.x;
    const int lane = tid & 63;
    const int wave = tid >> 6;
    const int wm = wave >> 1;
    const int wn = wave & 1;
    const int lr = lane & 15;
    const int ko2 = (lane >> 4) * 16;
    const int rbase = lr * 64 + (ko2 ^ (((lr >> 1) & 3) << 4));

    const int o0 = tid * 16;
    const int ol = o0 ^ (((o0 >> 7) & 3) << 4);
    const int sr = (ol >> 10) * 16 + ((ol >> 6) & 15);
    const int sc = (ol & 63) >> 1;

    const bf16_t* Abase = A + trow0 * K;
    const bf16_t* Bbase = B + tcol0 * K;

#define STAGE_A(kt, bufp) do {                                                        \
    gload_lds16(Abase + (long)sr * K         + ((kt) * 32 + sc), (bufp) + o0);        \
    gload_lds16(Abase + (long)(128 + sr) * K + ((kt) * 32 + sc), (bufp) + 8192 + o0); \
} while (0)
#define STAGE_B(kt, bufp) do {                                                        \
    gload_lds16(Bbase + (long)sr * K + ((kt) * 32 + sc), (bufp) + 16384 + o0);        \
} while (0)

    f32x4 acc[4][4];
#pragma unroll
    for (int i = 0; i < 4; ++i)
#pragma unroll
        for (int j = 0; j < 4; ++j)
            acc[i][j] = (f32x4){0.f, 0.f, 0.f, 0.f};

    // prologue: tiles 0,1 staged (3 loads each); vmcnt(3) => tile 0 landed.
    STAGE_A(0, sm);             STAGE_B(0, sm);
    STAGE_A(1, sm + 24576);     STAGE_B(1, sm + 24576);
    asm volatile("s_waitcnt vmcnt(3)" ::: "memory");
    BAR();

    const int NT = K / 32;
    int bi = 0;                  // t % 3
    for (int t = 0; t < NT; ++t) {
        char* cur = sm + bi * 24576;
        const int bn = (bi + 2 >= 3) ? bi - 1 : bi + 2;   // (t+2) % 3
        char* nxt = sm + bn * 24576;

        bf16x8 af_[4], bv_[4];
        af_[0] = *(const bf16x8*)(cur + (wm * 4 + 0) * 1024 + rbase);
        bv_[0] = *(const bf16x8*)(cur + 16384 + (wn * 2 + 0) * 1024 + rbase);
        bv_[1] = *(const bf16x8*)(cur + 16384 + (wn * 2 + 1) * 1024 + rbase);
#pragma unroll
        for (int i = 1; i < 4; ++i)
            af_[i] = *(const bf16x8*)(cur + (wm * 4 + i) * 1024 + rbase);
        bv_[2] = *(const bf16x8*)(cur + 16384 + (4 + wn * 2 + 0) * 1024 + rbase);
        bv_[3] = *(const bf16x8*)(cur + 16384 + (4 + wn * 2 + 1) * 1024 + rbase);
        if (t + 2 < NT) { STAGE_A(t + 2, nxt); STAGE_B(t + 2, nxt); }
        BAR();
        LGKM0();
        __builtin_amdgcn_s_setprio(1);
#pragma unroll
        for (int i = 0; i < 4; ++i)
#pragma unroll
            for (int j = 0; j < 4; ++j)
                acc[i][j] = __builtin_amdgcn_mfma_f32_16x16x32_bf16(
                    af_[i], bv_[j], acc[i][j], 0, 0, 0);
        __builtin_amdgcn_s_setprio(0);
        __builtin_amdgcn_sched_barrier(0);
        if (t + 2 < NT) { asm volatile("s_waitcnt vmcnt(3)" ::: "memory"); }
        else            { asm volatile("s_waitcnt vmcnt(0)" ::: "memory"); }
        BAR();
        bi = (bi == 2) ? 0 : bi + 1;
    }

    const int erow = (lane >> 4) * 4;
    const int ecol = lane & 15;
#pragma unroll
    for (int i = 0; i < 4; ++i)
#pragma unroll
        for (int j = 0; j < 4; ++j)
#pragma unroll
            for (int r = 0; r < 4; ++r) {
                long row = trow0 + wm * 64 + i * 16 + erow + r;
                long col = tcol0 + (j >> 1) * 64 + wn * 32 + (j & 1) * 16 + ecol;
                float s = acc[i][j][r] * scale;
                if (ACT) s = s * s * 0.1f + s * 0.1f;
                C[row * N + col] = (CT)s;
            }
#undef STAGE_A
#undef STAGE_B
}

// -----------------------------------------------------------------------------------
extern "C" void kernel_launch(void* const* d_in, const int* in_sizes, int n_in,
                              void* d_out, int out_size, void* d_ws, size_t ws_size,
                              hipStream_t stream) {
    const int*   x    = (const int*)d_in[0];
    const float* emb  = (const float*)d_in[1];
    const float* wq   = (const float*)d_in[2];
    const float* wk   = (const float*)d_in[3];
    const float* wv   = (const float*)d_in[4];
    const float* wo   = (const float*)d_in[5];
    const float* wout = (const float*)d_in[6];
    float* logits = (float*)d_out;

    char* ws = (char*)d_ws;
    size_t off = 0;
    auto alloc = [&](size_t bytes) {
        char* p = ws + off;
        off += (bytes + 255) & ~(size_t)255;
        return p;
    };
    bf16_t* hb    = (bf16_t*)alloc((size_t)BT * DIM * 2);
    bf16_t* qkb   = (bf16_t*)alloc((size_t)BT * 2 * DIM * 2);     // [8192, 2048] q|k
    bf16_t* vtb   = (bf16_t*)alloc((size_t)BATCH * DIM * SEQ * 2);
    bf16_t* attnb = (bf16_t*)alloc((size_t)BATCH * SEQ * SEQ * 2);
    bf16_t* o1b   = (bf16_t*)alloc((size_t)BT * DIM * 2);
    bf16_t* o2b   = (bf16_t*)alloc((size_t)BT * DIM * 2);
    bf16_t* wqkb  = (bf16_t*)alloc((size_t)2 * DIM * DIM * 2);    // [wq; wk] stacked
    bf16_t* wvb   = (bf16_t*)alloc((size_t)DIM * DIM * 2);
    bf16_t* wob   = (bf16_t*)alloc((size_t)DIM * DIM * 2);
    bf16_t* woutb = (bf16_t*)alloc((size_t)VOCAB * DIM * 2);

    {
        int n4 = DIM * DIM / 4;
        // 4 small weight casts in one dispatch (wq, wk into stacked wqkb; wv; wo)
        cast4_f32_to_bf16<<<dim3(n4 / 256, 4), 256, 0, stream>>>(
            wq, wk, wv, wo,
            wqkb, wqkb + (size_t)DIM * DIM, wvb, wob, n4);
        int n4o = VOCAB * DIM / 4;
        cast_f32_to_bf16<<<n4o / 256, 256, 0, stream>>>(wout, woutb, n4o);
    }

    embed_gather<<<BT, 256, 0, stream>>>(x, emb, hb);

    // fused q|k = 0.01 * h @ [wq;wk]^T -> qkb[8192,2048]; 512 blocks = 2/CU
    gemm_bt_256x128<0, 0, bf16_t><<<dim3((BT / 256) * (2 * DIM / 128), 1, 1), 512, 0, stream>>>(
        hb, wqkb, qkb, 2 * DIM, DIM, 0, 0, 0, 0.01f);

    // v^T[b] = 0.1 * wv @ h[b]^T: per-batch 4x16 = 64 blocks (SWZ=2)
    gemm_bt_256x128<0, 2, bf16_t><<<dim3(64, 1, BATCH), 512, 0, stream>>>(
        wvb, hb, vtb, SEQ, DIM, 0, (long)SEQ * DIM, (long)DIM * SEQ, 0.1f);

    // attn = fhe_act(0.01 * q[b] @ k[b]^T), q/k strided views of qkb (lda=2048)
    gemm_bt_256<1, 1, bf16_t><<<dim3(64, 1, BATCH), 512, 0, stream>>>(
        qkb, qkb + DIM, attnb, SEQ, DIM, 2 * DIM, 2 * DIM,
        (long)SEQ * 2 * DIM, (long)SEQ * 2 * DIM, (long)SEQ * SEQ, 0.01f);

    // o1 = 0.01 * attn[b] @ vT[b]^T: per-batch 8x8 = 64 blocks (SWZ=1), K=2048
    gemm_bt_256x128<0, 1, bf16_t><<<dim3(64, 1, BATCH), 512, 0, stream>>>(
        attnb, vtb, o1b, DIM, SEQ,
        (long)SEQ * SEQ, (long)DIM * SEQ, (long)SEQ * DIM, 0.01f);

    // o2 = 0.1 * o1 @ wo^T: 32x8 = 256 blocks (SWZ=0)
    gemm_bt_256x128<0, 0, bf16_t><<<dim3((BT / 256) * (DIM / 128), 1, 1), 512, 0, stream>>>(
        o1b, wob, o2b, DIM, DIM, 0, 0, 0, 0.1f);

    // logits = o2 @ wout^T: 32 * 250 = 8000 blocks, 2/CU
    gemm_bt_256x128<0, 0, float><<<dim3((BT / 256) * (VOCAB / 128), 1, 1), 512, 0, stream>>>(
        o2b, woutb, logits, VOCAB, DIM, 0, 0, 0, 1.0f);
}